// Round 12
// baseline (49.988 us; speedup 1.0000x reference)
//
#include <hip/hip_runtime.h>
#include <hip/hip_bf16.h>

#define NN 4096
#define FF 512
#define RR 64
#define HH 8
#define HR (HH * RR)     // 512
#define CAP 128
#define ATT_STRIDE 132   // h*132 % 32 = h*4 -> 8 heads hit 8 distinct banks

typedef short bf16x8 __attribute__((ext_vector_type(8)));
typedef float f32x4 __attribute__((ext_vector_type(4)));

__device__ __forceinline__ unsigned short f2bf(float f) {
  __hip_bfloat16 h = __float2bfloat16(f);   // RNE
  return *reinterpret_cast<unsigned short*>(&h);
}
__device__ __forceinline__ float bf2f(unsigned short u) {
  union { unsigned u32; float f; } cv;
  cv.u32 = ((unsigned)u) << 16;
  return cv.f;
}
__device__ __forceinline__ float lo2f(int w) {
  union { int i; float f; } c; c.i = w << 16; return c.f;
}
__device__ __forceinline__ float hi2f(int w) {
  union { int i; float f; } c; c.i = w & 0xffff0000; return c.f;
}
__device__ __forceinline__ float4 ntload4(const float* p) {
  const f32x4 v = __builtin_nontemporal_load(reinterpret_cast<const f32x4*>(p));
  return make_float4(v.x, v.y, v.z, v.w);
}
__device__ __forceinline__ unsigned nib4(const float4 v) {
  unsigned m = 0;
  if (v.x != 0.f) m |= 1u;
  if (v.y != 0.f) m |= 2u;
  if (v.z != 0.f) m |= 4u;
  if (v.w != 0.f) m |= 8u;
  return m;
}

// ---------------------------------------------------------------------------
// K_A: fused streaming. blocks [0,1024): adjacency compaction (4 rows/block,
// NT loads, tail zero-padded); [1024,3072): X fp32->bf16; [3072,3136): W
// transpose-convert via LDS tile.
// ---------------------------------------------------------------------------
__global__ __launch_bounds__(256) void k_stream(
    const float* __restrict__ X, const float* __restrict__ W,
    const float* __restrict__ adj,
    unsigned short* __restrict__ Xb, unsigned short* __restrict__ BbT,
    int* __restrict__ colsG, int* __restrict__ cnts)
{
  __shared__ unsigned short wt[64][68];
  const int b = blockIdx.x;
  const int tid = threadIdx.x;

  if (b < 1024) {
    const int lane = tid & 63;
    const int row = b * 4 + (tid >> 6);
    const float* arow = adj + (size_t)row * NN;
    unsigned long long pm = 0;
    {
      float4 buf[8];
#pragma unroll
      for (int c = 0; c < 8; ++c)
        buf[c] = ntload4(&arow[c * 256 + (lane << 2)]);
#pragma unroll
      for (int c = 0; c < 8; ++c)
        pm |= (unsigned long long)nib4(buf[c]) << (4 * c);
#pragma unroll
      for (int c = 0; c < 8; ++c)
        buf[c] = ntload4(&arow[(c + 8) * 256 + (lane << 2)]);
#pragma unroll
      for (int c = 0; c < 8; ++c)
        pm |= (unsigned long long)nib4(buf[c]) << (4 * c + 32);
    }
    const int cnt = __popcll(pm);
    int pfx = cnt;
#pragma unroll
    for (int off = 1; off < 64; off <<= 1) {
      const int o = __shfl_up(pfx, off);
      if (lane >= off) pfx += o;
    }
    int pos = pfx - cnt;
    unsigned long long m = pm;
    int* cg = colsG + (size_t)row * CAP;
    while (m) {
      const int bit = (int)__builtin_ctzll(m);
      m &= m - 1;
      if (pos < CAP) cg[pos] = ((bit >> 2) << 8) + (lane << 2) + (bit & 3);
      ++pos;
    }
    const int tot = __shfl(pfx, 63);
    for (int p = tot + lane; p < CAP; p += 64) cg[p] = 0;
    if (lane == 63) cnts[row] = tot < CAP ? tot : CAP;
  } else if (b < 3072) {
    const int t = (b - 1024) * 256 + tid;
    const float4 v = reinterpret_cast<const float4*>(X)[t];
    ushort4 u;
    u.x = f2bf(v.x); u.y = f2bf(v.y); u.z = f2bf(v.z); u.w = f2bf(v.w);
    reinterpret_cast<ushort4*>(Xb)[t] = u;
  } else {
    const int b2 = b - 3072;
    const int h = b2 >> 3;
    const int f0 = (b2 & 7) << 6;
    const int fr = tid >> 2;
    const int rq = (tid & 3) << 4;
    const float* wp = W + (size_t)h * FF * RR + (size_t)(f0 + fr) * RR + rq;
#pragma unroll
    for (int v = 0; v < 4; ++v) {
      const float4 x = *reinterpret_cast<const float4*>(wp + v * 4);
      wt[rq + v * 4 + 0][fr] = f2bf(x.x);
      wt[rq + v * 4 + 1][fr] = f2bf(x.y);
      wt[rq + v * 4 + 2][fr] = f2bf(x.z);
      wt[rq + v * 4 + 3][fr] = f2bf(x.w);
    }
    __syncthreads();
    const int r = tid >> 2;
    unsigned short* op = BbT + (size_t)(h * 64 + r) * FF + f0 + ((tid & 3) << 4);
    int4 w0 = *reinterpret_cast<const int4*>(&wt[r][(tid & 3) << 4]);
    int4 w1 = *reinterpret_cast<const int4*>(&wt[r][((tid & 3) << 4) + 8]);
    *reinterpret_cast<int4*>(op) = w0;
    *reinterpret_cast<int4*>(op + 8) = w1;
  }
}

// ---------------------------------------------------------------------------
// K_B: MFMA GEMM, double-buffered LDS, 1 barrier/K-tile, next-tile loads
// issued before compute. + fused a_srcT/a_dstT epilogue.
// ---------------------------------------------------------------------------
__global__ __launch_bounds__(256) void k_gemm_hidden(
    const unsigned short* __restrict__ Xb,
    const unsigned short* __restrict__ BbT,
    const float* __restrict__ sa,
    unsigned short* __restrict__ hiddenT,
    float* __restrict__ a_srcT,
    float* __restrict__ a_dstT)
{
  const int row0 = blockIdx.x * 64;
  const int h = blockIdx.y;
  const int n0 = h * 64;
  __shared__ unsigned short Als[2][64 * 32];
  __shared__ unsigned short Bls[2][64 * 32];
  __shared__ float redS[64][2];
  __shared__ float redD[64][2];
  const int tid = threadIdx.x;
  const int l = tid & 63;
  const int wid = tid >> 6;
  const int wr = wid >> 1, wc = wid & 1;

  f32x4 acc[2][2];
#pragma unroll
  for (int a = 0; a < 2; ++a)
#pragma unroll
    for (int bb = 0; bb < 2; ++bb) acc[a][bb] = (f32x4){0.f, 0.f, 0.f, 0.f};

  const int srow = tid >> 2;
  const int skel = (tid & 3) * 8;
  const unsigned short* xp = &Xb[(size_t)(row0 + srow) * FF + skel];
  const unsigned short* bp = &BbT[(size_t)(n0 + srow) * FF + skel];

  int4 av = *reinterpret_cast<const int4*>(xp);
  int4 bv = *reinterpret_cast<const int4*>(bp);

  int cur = 0;
  for (int k0 = 0; k0 < FF; k0 += 32) {
    *reinterpret_cast<int4*>(&Als[cur][tid * 8]) = av;
    *reinterpret_cast<int4*>(&Bls[cur][tid * 8]) = bv;
    __syncthreads();
    if (k0 + 32 < FF) {
      av = *reinterpret_cast<const int4*>(xp + k0 + 32);
      bv = *reinterpret_cast<const int4*>(bp + k0 + 32);
    }
    const int ka = (l >> 4) * 8;
    const bf16x8 a0 = *reinterpret_cast<const bf16x8*>(&Als[cur][(32 * wr + 0  + (l & 15)) * 32 + ka]);
    const bf16x8 a1 = *reinterpret_cast<const bf16x8*>(&Als[cur][(32 * wr + 16 + (l & 15)) * 32 + ka]);
    const bf16x8 b0 = *reinterpret_cast<const bf16x8*>(&Bls[cur][(32 * wc + 0  + (l & 15)) * 32 + ka]);
    const bf16x8 b1 = *reinterpret_cast<const bf16x8*>(&Bls[cur][(32 * wc + 16 + (l & 15)) * 32 + ka]);
    acc[0][0] = __builtin_amdgcn_mfma_f32_16x16x32_bf16(a0, b0, acc[0][0], 0, 0, 0);
    acc[0][1] = __builtin_amdgcn_mfma_f32_16x16x32_bf16(a0, b1, acc[0][1], 0, 0, 0);
    acc[1][0] = __builtin_amdgcn_mfma_f32_16x16x32_bf16(a1, b0, acc[1][0], 0, 0, 0);
    acc[1][1] = __builtin_amdgcn_mfma_f32_16x16x32_bf16(a1, b1, acc[1][1], 0, 0, 0);
    cur ^= 1;
  }

  const int lg = l >> 4;
  const int lc = l & 15;

#pragma unroll
  for (int mi = 0; mi < 2; ++mi)
#pragma unroll
    for (int ni = 0; ni < 2; ++ni)
#pragma unroll
      for (int j = 0; j < 4; ++j) {
        const int rowg = row0 + 32 * wr + 16 * mi + (lg << 2) + j;
        const int colg = n0 + 32 * wc + 16 * ni + lc;
        hiddenT[(size_t)rowg * HR + colg] = f2bf(acc[mi][ni][j]);
      }

  float sS[2], sD[2];
#pragma unroll
  for (int ni = 0; ni < 2; ++ni) {
    const int col = 32 * wc + 16 * ni + lc;
    sS[ni] = sa[(size_t)h * 2 * RR + col];
    sD[ni] = sa[(size_t)h * 2 * RR + RR + col];
  }
#pragma unroll
  for (int mi = 0; mi < 2; ++mi)
#pragma unroll
    for (int j = 0; j < 4; ++j) {
      float ps = acc[mi][0][j] * sS[0] + acc[mi][1][j] * sS[1];
      float pd = acc[mi][0][j] * sD[0] + acc[mi][1][j] * sD[1];
#pragma unroll
      for (int off = 8; off >= 1; off >>= 1) {
        ps += __shfl_xor(ps, off);
        pd += __shfl_xor(pd, off);
      }
      if (lc == 0) {
        const int rl = 32 * wr + 16 * mi + (lg << 2) + j;
        redS[rl][wc] = ps;
        redD[rl][wc] = pd;
      }
    }
  __syncthreads();
  if (tid < 64) {
    a_srcT[(size_t)(row0 + tid) * HH + h] = redS[tid][0] + redS[tid][1];
    a_dstT[(size_t)(row0 + tid) * HH + h] = redD[tid][0] + redD[tid][1];
  }
}

// ---------------------------------------------------------------------------
// K_C: one 256-thread block per row. Unconditional entry gathers; in-register
// softmax (-inf padded, __expf); 8-way agg with int4 loads.
// ---------------------------------------------------------------------------
__global__ __launch_bounds__(256) void k_gat_row(
    const int* __restrict__ colsG,
    const int* __restrict__ cnts,
    const float* __restrict__ bias,
    const float* __restrict__ a_srcT,
    const float* __restrict__ a_dstT,
    const unsigned short* __restrict__ hiddenT,
    float* __restrict__ out)
{
  const int i = blockIdx.x;
  const int tid = threadIdx.x;

  __shared__ __align__(16) float att[HH][ATT_STRIDE];
  __shared__ int cols[CAP];
  __shared__ __align__(16) float accred[8][HR];

  int c = 0;
  float4 d0, d1;
  float b = 0.f;
  if (tid < CAP) c = colsG[(size_t)i * CAP + tid];
  const int count = cnts[i];
  if (tid < CAP) {
    b = 0.01f * bias[(size_t)i * NN + c];
    d0 = *reinterpret_cast<const float4*>(&a_dstT[(size_t)c * HH]);
    d1 = *reinterpret_cast<const float4*>(&a_dstT[(size_t)c * HH + 4]);
  }
  const float4 s0 = *reinterpret_cast<const float4*>(&a_srcT[(size_t)i * HH]);
  const float4 s1 = *reinterpret_cast<const float4*>(&a_srcT[(size_t)i * HH + 4]);

  if (tid < CAP) {
    cols[tid] = c;
    float s;
    s = s0.x + d0.x + b; att[0][tid] = (s >= 0.f) ? s : 0.2f * s;
    s = s0.y + d0.y + b; att[1][tid] = (s >= 0.f) ? s : 0.2f * s;
    s = s0.z + d0.z + b; att[2][tid] = (s >= 0.f) ? s : 0.2f * s;
    s = s0.w + d0.w + b; att[3][tid] = (s >= 0.f) ? s : 0.2f * s;
    s = s1.x + d1.x + b; att[4][tid] = (s >= 0.f) ? s : 0.2f * s;
    s = s1.y + d1.y + b; att[5][tid] = (s >= 0.f) ? s : 0.2f * s;
    s = s1.z + d1.z + b; att[6][tid] = (s >= 0.f) ? s : 0.2f * s;
    s = s1.w + d1.w + b; att[7][tid] = (s >= 0.f) ? s : 0.2f * s;
  }
  __syncthreads();

  // ---- softmax: 32-lane group g owns head g; values in registers ----
  {
    const int g = tid >> 5;
    const int l = tid & 31;
    float v[4];
#pragma unroll
    for (int j = 0; j < 4; ++j) {
      const int t = l + j * 32;
      v[j] = (t < count) ? att[g][t] : -3.0e38f;
    }
    float m = fmaxf(fmaxf(v[0], v[1]), fmaxf(v[2], v[3]));
#pragma unroll
    for (int o = 16; o >= 1; o >>= 1) m = fmaxf(m, __shfl_xor(m, o));
    float e[4];
    float ssum = 0.f;
#pragma unroll
    for (int j = 0; j < 4; ++j) {
      e[j] = __expf(v[j] - m);
      ssum += e[j];
    }
#pragma unroll
    for (int o = 16; o >= 1; o >>= 1) ssum += __shfl_xor(ssum, o);
    const float inv = 1.0f / ssum;
#pragma unroll
    for (int j = 0; j < 4; ++j) att[g][l + j * 32] = e[j] * inv;
  }
  __syncthreads();

  // ---- aggregation: 8 groups of 32; thread owns 16 outputs ----
  {
    const int g2 = tid >> 5;
    const int o0 = (tid & 31) << 4;
    const float* attrow = att[o0 >> 6];
    const unsigned short* hb = hiddenT + o0;
    const int q = (count + 7) >> 3;
    const int t0 = g2 * q;
    const int t1 = min(t0 + q, count);
    float acc[16];
#pragma unroll
    for (int j = 0; j < 16; ++j) acc[j] = 0.f;
    for (int t = t0; t < t1; ++t) {
      const int cc = cols[t];
      const float a = attrow[t];
      const unsigned short* hp = hb + (size_t)cc * HR;
      const int4 u0 = *reinterpret_cast<const int4*>(hp);
      const int4 u1 = *reinterpret_cast<const int4*>(hp + 8);
      acc[0]  += a * lo2f(u0.x); acc[1]  += a * hi2f(u0.x);
      acc[2]  += a * lo2f(u0.y); acc[3]  += a * hi2f(u0.y);
      acc[4]  += a * lo2f(u0.z); acc[5]  += a * hi2f(u0.z);
      acc[6]  += a * lo2f(u0.w); acc[7]  += a * hi2f(u0.w);
      acc[8]  += a * lo2f(u1.x); acc[9]  += a * hi2f(u1.x);
      acc[10] += a * lo2f(u1.y); acc[11] += a * hi2f(u1.y);
      acc[12] += a * lo2f(u1.z); acc[13] += a * hi2f(u1.z);
      acc[14] += a * lo2f(u1.w); acc[15] += a * hi2f(u1.w);
    }
#pragma unroll
    for (int j = 0; j < 4; ++j) {
      float4 v = make_float4(acc[j * 4], acc[j * 4 + 1], acc[j * 4 + 2], acc[j * 4 + 3]);
      *reinterpret_cast<float4*>(&accred[g2][o0 + j * 4]) = v;
    }
  }
  __syncthreads();
  {
    const int o = tid << 1;
    float r0 = 0.f, r1 = 0.f;
#pragma unroll
    for (int g = 0; g < 8; ++g) {
      const float2 v = *reinterpret_cast<const float2*>(&accred[g][o]);
      r0 += v.x; r1 += v.y;
    }
    *reinterpret_cast<float2*>(&out[(size_t)i * HR + o]) = make_float2(r0, r1);
  }
}

extern "C" void kernel_launch(void* const* d_in, const int* in_sizes, int n_in,
                              void* d_out, int out_size, void* d_ws, size_t ws_size,
                              hipStream_t stream) {
  const float* X    = (const float*)d_in[0];   // [N,F]
  const float* adj  = (const float*)d_in[1];   // [N,N]
  const float* W    = (const float*)d_in[2];   // [H,F,R]
  const float* sa   = (const float*)d_in[3];   // [H,2R]
  const float* bias = (const float*)d_in[4];   // [N,N]
  float* out = (float*)d_out;                  // [N, H*R]

  unsigned short* hiddenT = (unsigned short*)d_ws;        // [N][512] bf16, 4 MB
  unsigned short* Xb  = hiddenT + (size_t)NN * HR;        // [N][512] bf16, 4 MB
  unsigned short* BbT = Xb + (size_t)NN * FF;             // [512][512] bf16, 512 KB
  float* a_srcT = (float*)(BbT + (size_t)HR * FF);        // [N][H], 128 KB
  float* a_dstT = a_srcT + (size_t)NN * HH;               // [N][H], 128 KB
  int* cnts     = (int*)(a_dstT + (size_t)NN * HH);       // [N], 16 KB
  int* colsG    = cnts + NN;                              // [N][CAP], 2 MB

  k_stream<<<dim3(3136), 256, 0, stream>>>(X, W, adj, Xb, BbT, colsG, cnts);
  k_gemm_hidden<<<dim3(NN / 64, HH), 256, 0, stream>>>(Xb, BbT, sa, hiddenT, a_srcT, a_dstT);
  k_gat_row<<<dim3(NN), 256, 0, stream>>>(colsG, cnts, bias, a_srcT, a_dstT, hiddenT, out);
}

// Round 13
// 49.168 us; speedup vs baseline: 1.0167x; 1.0167x over previous
//
#include <hip/hip_runtime.h>
#include <hip/hip_bf16.h>

#define NN 4096
#define FF 512
#define RR 64
#define HH 8
#define HR (HH * RR)     // 512
#define CAP 128
#define ATT_STRIDE 132

typedef short bf16x8 __attribute__((ext_vector_type(8)));
typedef float f32x4 __attribute__((ext_vector_type(4)));

__device__ __forceinline__ unsigned short f2bf(float f) {
  __hip_bfloat16 h = __float2bfloat16(f);   // RNE
  return *reinterpret_cast<unsigned short*>(&h);
}
__device__ __forceinline__ float lo2f(int w) {
  union { int i; float f; } c; c.i = w << 16; return c.f;
}
__device__ __forceinline__ float hi2f(int w) {
  union { int i; float f; } c; c.i = w & 0xffff0000; return c.f;
}
__device__ __forceinline__ unsigned nib4(const float4 v) {
  unsigned m = 0;
  if (v.x != 0.f) m |= 1u;
  if (v.y != 0.f) m |= 2u;
  if (v.z != 0.f) m |= 4u;
  if (v.w != 0.f) m |= 8u;
  return m;
}

// ---------------------------------------------------------------------------
// K_A: fused streaming. blocks [0,1024): adjacency compaction (4 rows/block,
// tail zero-padded); [1024,3072): X fp32->bf16; [3072,3136): W transpose.
// ---------------------------------------------------------------------------
__global__ __launch_bounds__(256) void k_stream(
    const float* __restrict__ X, const float* __restrict__ W,
    const float* __restrict__ adj,
    unsigned short* __restrict__ Xb, unsigned short* __restrict__ BbT,
    int* __restrict__ colsG, int* __restrict__ cnts)
{
  __shared__ unsigned short wt[64][68];
  const int b = blockIdx.x;
  const int tid = threadIdx.x;

  if (b < 1024) {
    const int lane = tid & 63;
    const int row = b * 4 + (tid >> 6);
    const float* arow = adj + (size_t)row * NN;
    unsigned long long pm = 0;
    {
      float4 buf[8];
#pragma unroll
      for (int c = 0; c < 8; ++c)
        buf[c] = *reinterpret_cast<const float4*>(&arow[c * 256 + (lane << 2)]);
#pragma unroll
      for (int c = 0; c < 8; ++c)
        pm |= (unsigned long long)nib4(buf[c]) << (4 * c);
#pragma unroll
      for (int c = 0; c < 8; ++c)
        buf[c] = *reinterpret_cast<const float4*>(&arow[(c + 8) * 256 + (lane << 2)]);
#pragma unroll
      for (int c = 0; c < 8; ++c)
        pm |= (unsigned long long)nib4(buf[c]) << (4 * c + 32);
    }
    const int cnt = __popcll(pm);
    int pfx = cnt;
#pragma unroll
    for (int off = 1; off < 64; off <<= 1) {
      const int o = __shfl_up(pfx, off);
      if (lane >= off) pfx += o;
    }
    int pos = pfx - cnt;
    unsigned long long m = pm;
    int* cg = colsG + (size_t)row * CAP;
    while (m) {
      const int bit = (int)__builtin_ctzll(m);
      m &= m - 1;
      if (pos < CAP) cg[pos] = ((bit >> 2) << 8) + (lane << 2) + (bit & 3);
      ++pos;
    }
    const int tot = __shfl(pfx, 63);
    for (int p = tot + lane; p < CAP; p += 64) cg[p] = 0;
    if (lane == 63) cnts[row] = tot < CAP ? tot : CAP;
  } else if (b < 3072) {
    const int t = (b - 1024) * 256 + tid;
    const float4 v = reinterpret_cast<const float4*>(X)[t];
    ushort4 u;
    u.x = f2bf(v.x); u.y = f2bf(v.y); u.z = f2bf(v.z); u.w = f2bf(v.w);
    reinterpret_cast<ushort4*>(Xb)[t] = u;
  } else {
    const int b2 = b - 3072;
    const int h = b2 >> 3;
    const int f0 = (b2 & 7) << 6;
    const int fr = tid >> 2;
    const int rq = (tid & 3) << 4;
    const float* wp = W + (size_t)h * FF * RR + (size_t)(f0 + fr) * RR + rq;
#pragma unroll
    for (int v = 0; v < 4; ++v) {
      const float4 x = *reinterpret_cast<const float4*>(wp + v * 4);
      wt[rq + v * 4 + 0][fr] = f2bf(x.x);
      wt[rq + v * 4 + 1][fr] = f2bf(x.y);
      wt[rq + v * 4 + 2][fr] = f2bf(x.z);
      wt[rq + v * 4 + 3][fr] = f2bf(x.w);
    }
    __syncthreads();
    const int r = tid >> 2;
    unsigned short* op = BbT + (size_t)(h * 64 + r) * FF + f0 + ((tid & 3) << 4);
    int4 w0 = *reinterpret_cast<const int4*>(&wt[r][(tid & 3) << 4]);
    int4 w1 = *reinterpret_cast<const int4*>(&wt[r][((tid & 3) << 4) + 8]);
    *reinterpret_cast<int4*>(op) = w0;
    *reinterpret_cast<int4*>(op + 8) = w1;
  }
}

// ---------------------------------------------------------------------------
// K_B: MFMA GEMM, double-buffered LDS, 1 barrier/K-tile + fused epilogue.
// ---------------------------------------------------------------------------
__global__ __launch_bounds__(256) void k_gemm_hidden(
    const unsigned short* __restrict__ Xb,
    const unsigned short* __restrict__ BbT,
    const float* __restrict__ sa,
    unsigned short* __restrict__ hiddenT,
    float* __restrict__ a_srcT,
    float* __restrict__ a_dstT)
{
  const int row0 = blockIdx.x * 64;
  const int h = blockIdx.y;
  const int n0 = h * 64;
  __shared__ unsigned short Als[2][64 * 32];
  __shared__ unsigned short Bls[2][64 * 32];
  __shared__ float redS[64][2];
  __shared__ float redD[64][2];
  const int tid = threadIdx.x;
  const int l = tid & 63;
  const int wid = tid >> 6;
  const int wr = wid >> 1, wc = wid & 1;

  f32x4 acc[2][2];
#pragma unroll
  for (int a = 0; a < 2; ++a)
#pragma unroll
    for (int bb = 0; bb < 2; ++bb) acc[a][bb] = (f32x4){0.f, 0.f, 0.f, 0.f};

  const int srow = tid >> 2;
  const int skel = (tid & 3) * 8;
  const unsigned short* xp = &Xb[(size_t)(row0 + srow) * FF + skel];
  const unsigned short* bp = &BbT[(size_t)(n0 + srow) * FF + skel];

  int4 av = *reinterpret_cast<const int4*>(xp);
  int4 bv = *reinterpret_cast<const int4*>(bp);

  int cur = 0;
  for (int k0 = 0; k0 < FF; k0 += 32) {
    *reinterpret_cast<int4*>(&Als[cur][tid * 8]) = av;
    *reinterpret_cast<int4*>(&Bls[cur][tid * 8]) = bv;
    __syncthreads();
    if (k0 + 32 < FF) {
      av = *reinterpret_cast<const int4*>(xp + k0 + 32);
      bv = *reinterpret_cast<const int4*>(bp + k0 + 32);
    }
    const int ka = (l >> 4) * 8;
    const bf16x8 a0 = *reinterpret_cast<const bf16x8*>(&Als[cur][(32 * wr + 0  + (l & 15)) * 32 + ka]);
    const bf16x8 a1 = *reinterpret_cast<const bf16x8*>(&Als[cur][(32 * wr + 16 + (l & 15)) * 32 + ka]);
    const bf16x8 b0 = *reinterpret_cast<const bf16x8*>(&Bls[cur][(32 * wc + 0  + (l & 15)) * 32 + ka]);
    const bf16x8 b1 = *reinterpret_cast<const bf16x8*>(&Bls[cur][(32 * wc + 16 + (l & 15)) * 32 + ka]);
    acc[0][0] = __builtin_amdgcn_mfma_f32_16x16x32_bf16(a0, b0, acc[0][0], 0, 0, 0);
    acc[0][1] = __builtin_amdgcn_mfma_f32_16x16x32_bf16(a0, b1, acc[0][1], 0, 0, 0);
    acc[1][0] = __builtin_amdgcn_mfma_f32_16x16x32_bf16(a1, b0, acc[1][0], 0, 0, 0);
    acc[1][1] = __builtin_amdgcn_mfma_f32_16x16x32_bf16(a1, b1, acc[1][1], 0, 0, 0);
    cur ^= 1;
  }

  const int lg = l >> 4;
  const int lc = l & 15;

#pragma unroll
  for (int mi = 0; mi < 2; ++mi)
#pragma unroll
    for (int ni = 0; ni < 2; ++ni)
#pragma unroll
      for (int j = 0; j < 4; ++j) {
        const int rowg = row0 + 32 * wr + 16 * mi + (lg << 2) + j;
        const int colg = n0 + 32 * wc + 16 * ni + lc;
        hiddenT[(size_t)rowg * HR + colg] = f2bf(acc[mi][ni][j]);
      }

  float sS[2], sD[2];
#pragma unroll
  for (int ni = 0; ni < 2; ++ni) {
    const int col = 32 * wc + 16 * ni + lc;
    sS[ni] = sa[(size_t)h * 2 * RR + col];
    sD[ni] = sa[(size_t)h * 2 * RR + RR + col];
  }
#pragma unroll
  for (int mi = 0; mi < 2; ++mi)
#pragma unroll
    for (int j = 0; j < 4; ++j) {
      float ps = acc[mi][0][j] * sS[0] + acc[mi][1][j] * sS[1];
      float pd = acc[mi][0][j] * sD[0] + acc[mi][1][j] * sD[1];
#pragma unroll
      for (int off = 8; off >= 1; off >>= 1) {
        ps += __shfl_xor(ps, off);
        pd += __shfl_xor(pd, off);
      }
      if (lc == 0) {
        const int rl = 32 * wr + 16 * mi + (lg << 2) + j;
        redS[rl][wc] = ps;
        redD[rl][wc] = pd;
      }
    }
  __syncthreads();
  if (tid < 64) {
    a_srcT[(size_t)(row0 + tid) * HH + h] = redS[tid][0] + redS[tid][1];
    a_dstT[(size_t)(row0 + tid) * HH + h] = redD[tid][0] + redD[tid][1];
  }
}

// ---------------------------------------------------------------------------
// K_C: TWO rows per 256-thread block, software-pipelined: both rows' scattered
// prologue loads issued at entry; row B's latency hides under row A's compute.
// ---------------------------------------------------------------------------
__global__ __launch_bounds__(256) void k_gat_row(
    const int* __restrict__ colsG,
    const int* __restrict__ cnts,
    const float* __restrict__ bias,
    const float* __restrict__ a_srcT,
    const float* __restrict__ a_dstT,
    const unsigned short* __restrict__ hiddenT,
    float* __restrict__ out)
{
  const int iA = blockIdx.x * 2;
  const int iB = iA + 1;
  const int tid = threadIdx.x;

  __shared__ __align__(16) float att[HH][ATT_STRIDE];
  __shared__ int cols[CAP];
  __shared__ __align__(16) float accred[8][HR];

  // ---- prologue: ALL independent scattered loads for BOTH rows ----
  int cA = 0, cB = 0;
  if (tid < CAP) {
    cA = colsG[(size_t)iA * CAP + tid];
    cB = colsG[(size_t)iB * CAP + tid];
  }
  const int countA = cnts[iA];
  const int countB = cnts[iB];
  float bA = 0.f, bB = 0.f;
  float4 d0A, d1A, d0B, d1B;
  if (tid < CAP) {
    bA = 0.01f * bias[(size_t)iA * NN + cA];
    bB = 0.01f * bias[(size_t)iB * NN + cB];
    d0A = *reinterpret_cast<const float4*>(&a_dstT[(size_t)cA * HH]);
    d1A = *reinterpret_cast<const float4*>(&a_dstT[(size_t)cA * HH + 4]);
    d0B = *reinterpret_cast<const float4*>(&a_dstT[(size_t)cB * HH]);
    d1B = *reinterpret_cast<const float4*>(&a_dstT[(size_t)cB * HH + 4]);
  }
  const float4 s0A = *reinterpret_cast<const float4*>(&a_srcT[(size_t)iA * HH]);
  const float4 s1A = *reinterpret_cast<const float4*>(&a_srcT[(size_t)iA * HH + 4]);
  const float4 s0B = *reinterpret_cast<const float4*>(&a_srcT[(size_t)iB * HH]);
  const float4 s1B = *reinterpret_cast<const float4*>(&a_srcT[(size_t)iB * HH + 4]);

#pragma unroll
  for (int rr = 0; rr < 2; ++rr) {
    const int i = rr ? iB : iA;
    const int count = rr ? countB : countA;
    const int c = rr ? cB : cA;
    const float b = rr ? bB : bA;
    const float4 d0 = rr ? d0B : d0A;
    const float4 d1 = rr ? d1B : d1A;
    const float4 s0 = rr ? s0B : s0A;
    const float4 s1 = rr ? s1B : s1A;

    // ---- scores ----
    if (tid < CAP) {
      cols[tid] = c;
      float s;
      s = s0.x + d0.x + b; att[0][tid] = (s >= 0.f) ? s : 0.2f * s;
      s = s0.y + d0.y + b; att[1][tid] = (s >= 0.f) ? s : 0.2f * s;
      s = s0.z + d0.z + b; att[2][tid] = (s >= 0.f) ? s : 0.2f * s;
      s = s0.w + d0.w + b; att[3][tid] = (s >= 0.f) ? s : 0.2f * s;
      s = s1.x + d1.x + b; att[4][tid] = (s >= 0.f) ? s : 0.2f * s;
      s = s1.y + d1.y + b; att[5][tid] = (s >= 0.f) ? s : 0.2f * s;
      s = s1.z + d1.z + b; att[6][tid] = (s >= 0.f) ? s : 0.2f * s;
      s = s1.w + d1.w + b; att[7][tid] = (s >= 0.f) ? s : 0.2f * s;
    }
    __syncthreads();

    // ---- softmax: 32-lane group g owns head g; values in registers ----
    {
      const int g = tid >> 5;
      const int l = tid & 31;
      float v[4];
#pragma unroll
      for (int j = 0; j < 4; ++j) {
        const int t = l + j * 32;
        v[j] = (t < count) ? att[g][t] : -3.0e38f;
      }
      float m = fmaxf(fmaxf(v[0], v[1]), fmaxf(v[2], v[3]));
#pragma unroll
      for (int o = 16; o >= 1; o >>= 1) m = fmaxf(m, __shfl_xor(m, o));
      float e[4];
      float ssum = 0.f;
#pragma unroll
      for (int j = 0; j < 4; ++j) {
        e[j] = __expf(v[j] - m);
        ssum += e[j];
      }
#pragma unroll
      for (int o = 16; o >= 1; o >>= 1) ssum += __shfl_xor(ssum, o);
      const float inv = 1.0f / ssum;
#pragma unroll
      for (int j = 0; j < 4; ++j) att[g][l + j * 32] = e[j] * inv;
    }
    __syncthreads();

    // ---- aggregation: 8 groups of 32; thread owns 16 outputs ----
    {
      const int g2 = tid >> 5;
      const int o0 = (tid & 31) << 4;
      const float* attrow = att[o0 >> 6];
      const unsigned short* hb = hiddenT + o0;
      const int q = (count + 7) >> 3;
      const int t0 = g2 * q;
      const int t1 = min(t0 + q, count);
      float acc[16];
#pragma unroll
      for (int j = 0; j < 16; ++j) acc[j] = 0.f;
      for (int t = t0; t < t1; ++t) {
        const int cc = cols[t];
        const float a = attrow[t];
        const unsigned short* hp = hb + (size_t)cc * HR;
        const int4 u0 = *reinterpret_cast<const int4*>(hp);
        const int4 u1 = *reinterpret_cast<const int4*>(hp + 8);
        acc[0]  += a * lo2f(u0.x); acc[1]  += a * hi2f(u0.x);
        acc[2]  += a * lo2f(u0.y); acc[3]  += a * hi2f(u0.y);
        acc[4]  += a * lo2f(u0.z); acc[5]  += a * hi2f(u0.z);
        acc[6]  += a * lo2f(u0.w); acc[7]  += a * hi2f(u0.w);
        acc[8]  += a * lo2f(u1.x); acc[9]  += a * hi2f(u1.x);
        acc[10] += a * lo2f(u1.y); acc[11] += a * hi2f(u1.y);
        acc[12] += a * lo2f(u1.z); acc[13] += a * hi2f(u1.z);
        acc[14] += a * lo2f(u1.w); acc[15] += a * hi2f(u1.w);
      }
#pragma unroll
      for (int j = 0; j < 4; ++j) {
        float4 v = make_float4(acc[j * 4], acc[j * 4 + 1], acc[j * 4 + 2], acc[j * 4 + 3]);
        *reinterpret_cast<float4*>(&accred[g2][o0 + j * 4]) = v;
      }
    }
    __syncthreads();
    {
      const int o = tid << 1;
      float r0 = 0.f, r1 = 0.f;
#pragma unroll
      for (int g = 0; g < 8; ++g) {
        const float2 v = *reinterpret_cast<const float2*>(&accred[g][o]);
        r0 += v.x; r1 += v.y;
      }
      *reinterpret_cast<float2*>(&out[(size_t)i * HR + o]) = make_float2(r0, r1);
    }
  }
}

extern "C" void kernel_launch(void* const* d_in, const int* in_sizes, int n_in,
                              void* d_out, int out_size, void* d_ws, size_t ws_size,
                              hipStream_t stream) {
  const float* X    = (const float*)d_in[0];   // [N,F]
  const float* adj  = (const float*)d_in[1];   // [N,N]
  const float* W    = (const float*)d_in[2];   // [H,F,R]
  const float* sa   = (const float*)d_in[3];   // [H,2R]
  const float* bias = (const float*)d_in[4];   // [N,N]
  float* out = (float*)d_out;                  // [N, H*R]

  unsigned short* hiddenT = (unsigned short*)d_ws;        // [N][512] bf16, 4 MB
  unsigned short* Xb  = hiddenT + (size_t)NN * HR;        // [N][512] bf16, 4 MB
  unsigned short* BbT = Xb + (size_t)NN * FF;             // [512][512] bf16, 512 KB
  float* a_srcT = (float*)(BbT + (size_t)HR * FF);        // [N][H], 128 KB
  float* a_dstT = a_srcT + (size_t)NN * HH;               // [N][H], 128 KB
  int* cnts     = (int*)(a_dstT + (size_t)NN * HH);       // [N], 16 KB
  int* colsG    = cnts + NN;                              // [N][CAP], 2 MB

  k_stream<<<dim3(3136), 256, 0, stream>>>(X, W, adj, Xb, BbT, colsG, cnts);
  k_gemm_hidden<<<dim3(NN / 64, HH), 256, 0, stream>>>(Xb, BbT, sa, hiddenT, a_srcT, a_dstT);
  k_gat_row<<<dim3(NN / 2), 256, 0, stream>>>(colsG, cnts, bias, a_srcT, a_dstT, hiddenT, out);
}

// Round 14
// 46.110 us; speedup vs baseline: 1.0841x; 1.0663x over previous
//
#include <hip/hip_runtime.h>
#include <hip/hip_bf16.h>

#define NN 4096
#define FF 512
#define RR 64
#define HH 8
#define HR (HH * RR)     // 512
#define CAP 128
#define ATT_STRIDE 144

typedef short bf16x8 __attribute__((ext_vector_type(8)));
typedef float f32x4 __attribute__((ext_vector_type(4)));

__device__ __forceinline__ unsigned short f2bf(float f) {
  __hip_bfloat16 h = __float2bfloat16(f);   // RNE
  return *reinterpret_cast<unsigned short*>(&h);
}
__device__ __forceinline__ float bf2f(unsigned short u) {
  union { unsigned u32; float f; } cv;
  cv.u32 = ((unsigned)u) << 16;
  return cv.f;
}
__device__ __forceinline__ unsigned nib4(const float4 v) {
  unsigned m = 0;
  if (v.x != 0.f) m |= 1u;
  if (v.y != 0.f) m |= 2u;
  if (v.z != 0.f) m |= 4u;
  if (v.w != 0.f) m |= 8u;
  return m;
}

// ---------------------------------------------------------------------------
// K1: blocks [0,2048): X fp32->bf16; [2048,2112): W transpose-convert.
// ---------------------------------------------------------------------------
__global__ __launch_bounds__(256) void k_convert(
    const float* __restrict__ X, const float* __restrict__ W,
    unsigned short* __restrict__ Xb, unsigned short* __restrict__ BbT)
{
  __shared__ unsigned short wt[64][68];
  const int b = blockIdx.x;
  const int tid = threadIdx.x;

  if (b < 2048) {
    const int t = b * 256 + tid;
    const float4 v = reinterpret_cast<const float4*>(X)[t];
    ushort4 u;
    u.x = f2bf(v.x); u.y = f2bf(v.y); u.z = f2bf(v.z); u.w = f2bf(v.w);
    reinterpret_cast<ushort4*>(Xb)[t] = u;
  } else {
    const int b2 = b - 2048;
    const int h = b2 >> 3;
    const int f0 = (b2 & 7) << 6;
    const int fr = tid >> 2;
    const int rq = (tid & 3) << 4;
    const float* wp = W + (size_t)h * FF * RR + (size_t)(f0 + fr) * RR + rq;
#pragma unroll
    for (int v = 0; v < 4; ++v) {
      const float4 x = *reinterpret_cast<const float4*>(wp + v * 4);
      wt[rq + v * 4 + 0][fr] = f2bf(x.x);
      wt[rq + v * 4 + 1][fr] = f2bf(x.y);
      wt[rq + v * 4 + 2][fr] = f2bf(x.z);
      wt[rq + v * 4 + 3][fr] = f2bf(x.w);
    }
    __syncthreads();
    const int r = tid >> 2;
    unsigned short* op = BbT + (size_t)(h * 64 + r) * FF + f0 + ((tid & 3) << 4);
    int4 w0 = *reinterpret_cast<const int4*>(&wt[r][(tid & 3) << 4]);
    int4 w1 = *reinterpret_cast<const int4*>(&wt[r][((tid & 3) << 4) + 8]);
    *reinterpret_cast<int4*>(op) = w0;
    *reinterpret_cast<int4*>(op + 8) = w1;
  }
}

// ---------------------------------------------------------------------------
// K2 (mega): blocks [0,512): MFMA GEMM (R9-exact, reads Xb bf16) + fused
// a_srcT/a_dstT epilogue. blocks [512,1536): adjacency compaction (R9-exact,
// 4 rows/block, tail zero-padded). Stream hides under MFMA compute.
// ---------------------------------------------------------------------------
__global__ __launch_bounds__(256) void k_mega(
    const unsigned short* __restrict__ Xb,
    const unsigned short* __restrict__ BbT,
    const float* __restrict__ sa,
    const float* __restrict__ adj,
    unsigned short* __restrict__ hiddenT,
    float* __restrict__ a_srcT,
    float* __restrict__ a_dstT,
    int* __restrict__ colsG,
    int* __restrict__ cnts)
{
  __shared__ unsigned short Als[64 * 32];
  __shared__ unsigned short Bls[64 * 32];
  __shared__ float redS[64][2];
  __shared__ float redD[64][2];
  const int b = blockIdx.x;
  const int tid = threadIdx.x;

  if (b < 512) {
    const int row0 = (b & 63) * 64;
    const int h = b >> 6;
    const int n0 = h * 64;
    const int l = tid & 63;
    const int wid = tid >> 6;
    const int wr = wid >> 1, wc = wid & 1;

    f32x4 acc[2][2];
#pragma unroll
    for (int a = 0; a < 2; ++a)
#pragma unroll
      for (int bb = 0; bb < 2; ++bb) acc[a][bb] = (f32x4){0.f, 0.f, 0.f, 0.f};

    const int srow = tid >> 2;
    const int skel = (tid & 3) * 8;

    for (int k0 = 0; k0 < FF; k0 += 32) {
      const int4 av = *reinterpret_cast<const int4*>(
          &Xb[(size_t)(row0 + srow) * FF + k0 + skel]);
      const int4 bv = *reinterpret_cast<const int4*>(
          &BbT[(size_t)(n0 + srow) * FF + k0 + skel]);
      __syncthreads();
      *reinterpret_cast<int4*>(&Als[tid * 8]) = av;
      *reinterpret_cast<int4*>(&Bls[tid * 8]) = bv;
      __syncthreads();

      const int ka = (l >> 4) * 8;
      const bf16x8 a0 = *reinterpret_cast<const bf16x8*>(&Als[(32 * wr + 0  + (l & 15)) * 32 + ka]);
      const bf16x8 a1 = *reinterpret_cast<const bf16x8*>(&Als[(32 * wr + 16 + (l & 15)) * 32 + ka]);
      const bf16x8 b0 = *reinterpret_cast<const bf16x8*>(&Bls[(32 * wc + 0  + (l & 15)) * 32 + ka]);
      const bf16x8 b1 = *reinterpret_cast<const bf16x8*>(&Bls[(32 * wc + 16 + (l & 15)) * 32 + ka]);
      acc[0][0] = __builtin_amdgcn_mfma_f32_16x16x32_bf16(a0, b0, acc[0][0], 0, 0, 0);
      acc[0][1] = __builtin_amdgcn_mfma_f32_16x16x32_bf16(a0, b1, acc[0][1], 0, 0, 0);
      acc[1][0] = __builtin_amdgcn_mfma_f32_16x16x32_bf16(a1, b0, acc[1][0], 0, 0, 0);
      acc[1][1] = __builtin_amdgcn_mfma_f32_16x16x32_bf16(a1, b1, acc[1][1], 0, 0, 0);
    }

    const int lg = l >> 4;
    const int lc = l & 15;

#pragma unroll
    for (int mi = 0; mi < 2; ++mi)
#pragma unroll
      for (int ni = 0; ni < 2; ++ni)
#pragma unroll
        for (int j = 0; j < 4; ++j) {
          const int rowg = row0 + 32 * wr + 16 * mi + (lg << 2) + j;
          const int colg = n0 + 32 * wc + 16 * ni + lc;
          hiddenT[(size_t)rowg * HR + colg] = f2bf(acc[mi][ni][j]);
        }

    float sS[2], sD[2];
#pragma unroll
    for (int ni = 0; ni < 2; ++ni) {
      const int col = 32 * wc + 16 * ni + lc;
      sS[ni] = sa[(size_t)h * 2 * RR + col];
      sD[ni] = sa[(size_t)h * 2 * RR + RR + col];
    }
#pragma unroll
    for (int mi = 0; mi < 2; ++mi)
#pragma unroll
      for (int j = 0; j < 4; ++j) {
        float ps = acc[mi][0][j] * sS[0] + acc[mi][1][j] * sS[1];
        float pd = acc[mi][0][j] * sD[0] + acc[mi][1][j] * sD[1];
#pragma unroll
        for (int off = 8; off >= 1; off >>= 1) {
          ps += __shfl_xor(ps, off);
          pd += __shfl_xor(pd, off);
        }
        if (lc == 0) {
          const int rl = 32 * wr + 16 * mi + (lg << 2) + j;
          redS[rl][wc] = ps;
          redD[rl][wc] = pd;
        }
      }
    __syncthreads();
    if (tid < 64) {
      a_srcT[(size_t)(row0 + tid) * HH + h] = redS[tid][0] + redS[tid][1];
      a_dstT[(size_t)(row0 + tid) * HH + h] = redD[tid][0] + redD[tid][1];
    }
  } else {
    const int lane = tid & 63;
    const int row = (b - 512) * 4 + (tid >> 6);
    const float* arow = adj + (size_t)row * NN;
    unsigned long long pm = 0;
    {
      float4 buf[8];
#pragma unroll
      for (int c = 0; c < 8; ++c)
        buf[c] = *reinterpret_cast<const float4*>(&arow[c * 256 + (lane << 2)]);
#pragma unroll
      for (int c = 0; c < 8; ++c)
        pm |= (unsigned long long)nib4(buf[c]) << (4 * c);
#pragma unroll
      for (int c = 0; c < 8; ++c)
        buf[c] = *reinterpret_cast<const float4*>(&arow[(c + 8) * 256 + (lane << 2)]);
#pragma unroll
      for (int c = 0; c < 8; ++c)
        pm |= (unsigned long long)nib4(buf[c]) << (4 * c + 32);
    }
    const int cnt = __popcll(pm);
    int pfx = cnt;
#pragma unroll
    for (int off = 1; off < 64; off <<= 1) {
      const int o = __shfl_up(pfx, off);
      if (lane >= off) pfx += o;
    }
    int pos = pfx - cnt;
    unsigned long long m = pm;
    int* cg = colsG + (size_t)row * CAP;
    while (m) {
      const int bit = (int)__builtin_ctzll(m);
      m &= m - 1;
      if (pos < CAP) cg[pos] = ((bit >> 2) << 8) + (lane << 2) + (bit & 3);
      ++pos;
    }
    const int tot = __shfl(pfx, 63);
    for (int p = tot + lane; p < CAP; p += 64) cg[p] = 0;
    if (lane == 63) cnts[row] = tot < CAP ? tot : CAP;
  }
}

// ---------------------------------------------------------------------------
// K3: R9-exact k_gat_row. Unconditional entry gathers; LDS softmax; 4-way agg.
// ---------------------------------------------------------------------------
__global__ __launch_bounds__(256) void k_gat_row(
    const int* __restrict__ colsG,
    const int* __restrict__ cnts,
    const float* __restrict__ bias,
    const float* __restrict__ a_srcT,
    const float* __restrict__ a_dstT,
    const unsigned short* __restrict__ hiddenT,
    float* __restrict__ out)
{
  const int i = blockIdx.x;
  const int tid = threadIdx.x;

  __shared__ __align__(16) float att[HH][ATT_STRIDE];
  __shared__ int cols[CAP];
  __shared__ __align__(16) float accred[4][HR];

  int c = 0;
  float4 d0, d1;
  float b = 0.f;
  if (tid < CAP) c = colsG[(size_t)i * CAP + tid];
  const int count = cnts[i];
  if (tid < CAP) {
    b = 0.01f * bias[(size_t)i * NN + c];
    d0 = *reinterpret_cast<const float4*>(&a_dstT[(size_t)c * HH]);
    d1 = *reinterpret_cast<const float4*>(&a_dstT[(size_t)c * HH + 4]);
  }
  const float4 s0 = *reinterpret_cast<const float4*>(&a_srcT[(size_t)i * HH]);
  const float4 s1 = *reinterpret_cast<const float4*>(&a_srcT[(size_t)i * HH + 4]);

  if (tid < CAP) {
    cols[tid] = c;
    float s;
    s = s0.x + d0.x + b; att[0][tid] = (s >= 0.f) ? s : 0.2f * s;
    s = s0.y + d0.y + b; att[1][tid] = (s >= 0.f) ? s : 0.2f * s;
    s = s0.z + d0.z + b; att[2][tid] = (s >= 0.f) ? s : 0.2f * s;
    s = s0.w + d0.w + b; att[3][tid] = (s >= 0.f) ? s : 0.2f * s;
    s = s1.x + d1.x + b; att[4][tid] = (s >= 0.f) ? s : 0.2f * s;
    s = s1.y + d1.y + b; att[5][tid] = (s >= 0.f) ? s : 0.2f * s;
    s = s1.z + d1.z + b; att[6][tid] = (s >= 0.f) ? s : 0.2f * s;
    s = s1.w + d1.w + b; att[7][tid] = (s >= 0.f) ? s : 0.2f * s;
  }
  __syncthreads();

  {
    const int g = tid >> 5;
    const int l = tid & 31;
    float* arow_h = att[g];
    float m = -3.0e38f;
    for (int t = l; t < count; t += 32) m = fmaxf(m, arow_h[t]);
#pragma unroll
    for (int o = 16; o >= 1; o >>= 1) m = fmaxf(m, __shfl_xor(m, o));
    float ssum = 0.f;
    for (int t = l; t < count; t += 32) {
      const float e = expf(arow_h[t] - m);
      arow_h[t] = e;
      ssum += e;
    }
#pragma unroll
    for (int o = 16; o >= 1; o >>= 1) ssum += __shfl_xor(ssum, o);
    const float inv = 1.0f / ssum;
    for (int t = l; t < count; t += 32) arow_h[t] *= inv;
  }
  __syncthreads();

  {
    const int g2 = tid >> 6;
    const int o0 = (tid & 63) << 3;
    const float* attrow = att[o0 >> 6];
    const unsigned short* hb = hiddenT + o0;
    const int q = (count + 3) >> 2;
    const int t0 = g2 * q;
    const int t1 = min(t0 + q, count);
    float4 accA = make_float4(0.f, 0.f, 0.f, 0.f);
    float4 accB = make_float4(0.f, 0.f, 0.f, 0.f);
    for (int t = t0; t < t1; ++t) {
      const int cc = cols[t];
      const float a = attrow[t];
      const ushort4 ua = *reinterpret_cast<const ushort4*>(hb + (size_t)cc * HR);
      const ushort4 ub = *reinterpret_cast<const ushort4*>(hb + (size_t)cc * HR + 4);
      accA.x += a * bf2f(ua.x); accA.y += a * bf2f(ua.y);
      accA.z += a * bf2f(ua.z); accA.w += a * bf2f(ua.w);
      accB.x += a * bf2f(ub.x); accB.y += a * bf2f(ub.y);
      accB.z += a * bf2f(ub.z); accB.w += a * bf2f(ub.w);
    }
    *reinterpret_cast<float4*>(&accred[g2][o0]) = accA;
    *reinterpret_cast<float4*>(&accred[g2][o0 + 4]) = accB;
  }
  __syncthreads();
  {
    const int o = tid << 1;
    const float2 r = make_float2(
        accred[0][o] + accred[1][o] + accred[2][o] + accred[3][o],
        accred[0][o + 1] + accred[1][o + 1] + accred[2][o + 1] + accred[3][o + 1]);
    *reinterpret_cast<float2*>(&out[(size_t)i * HR + o]) = r;
  }
}

extern "C" void kernel_launch(void* const* d_in, const int* in_sizes, int n_in,
                              void* d_out, int out_size, void* d_ws, size_t ws_size,
                              hipStream_t stream) {
  const float* X    = (const float*)d_in[0];   // [N,F]
  const float* adj  = (const float*)d_in[1];   // [N,N]
  const float* W    = (const float*)d_in[2];   // [H,F,R]
  const float* sa   = (const float*)d_in[3];   // [H,2R]
  const float* bias = (const float*)d_in[4];   // [N,N]
  float* out = (float*)d_out;                  // [N, H*R]

  unsigned short* hiddenT = (unsigned short*)d_ws;        // [N][512] bf16, 4 MB
  unsigned short* Xb  = hiddenT + (size_t)NN * HR;        // [N][512] bf16, 4 MB
  unsigned short* BbT = Xb + (size_t)NN * FF;             // [512][512] bf16, 512 KB
  float* a_srcT = (float*)(BbT + (size_t)HR * FF);        // [N][H], 128 KB
  float* a_dstT = a_srcT + (size_t)NN * HH;               // [N][H], 128 KB
  int* cnts     = (int*)(a_dstT + (size_t)NN * HH);       // [N], 16 KB
  int* colsG    = cnts + NN;                              // [N][CAP], 2 MB

  k_convert<<<dim3(2112), 256, 0, stream>>>(X, W, Xb, BbT);
  k_mega<<<dim3(1536), 256, 0, stream>>>(Xb, BbT, sa, adj, hiddenT, a_srcT, a_dstT, colsG, cnts);
  k_gat_row<<<dim3(NN), 256, 0, stream>>>(colsG, cnts, bias, a_srcT, a_dstT, hiddenT, out);
}

// Round 15
// 44.243 us; speedup vs baseline: 1.1298x; 1.0422x over previous
//
#include <hip/hip_runtime.h>
#include <hip/hip_bf16.h>

#define NN 4096
#define FF 512
#define RR 64
#define HH 8
#define HR (HH * RR)     // 512
#define CAP 128
#define ATT_STRIDE 132

typedef short bf16x8 __attribute__((ext_vector_type(8)));
typedef float f32x4 __attribute__((ext_vector_type(4)));

__device__ __forceinline__ unsigned short f2bf(float f) {
  __hip_bfloat16 h = __float2bfloat16(f);   // RNE
  return *reinterpret_cast<unsigned short*>(&h);
}
__device__ __forceinline__ float bf2f(unsigned short u) {
  union { unsigned u32; float f; } cv;
  cv.u32 = ((unsigned)u) << 16;
  return cv.f;
}
__device__ __forceinline__ unsigned nib4(const float4 v) {
  unsigned m = 0;
  if (v.x != 0.f) m |= 1u;
  if (v.y != 0.f) m |= 2u;
  if (v.z != 0.f) m |= 4u;
  if (v.w != 0.f) m |= 8u;
  return m;
}

// ---------------------------------------------------------------------------
// K1: blocks [0,2048): X fp32->bf16; [2048,2112): W transpose-convert.
// ---------------------------------------------------------------------------
__global__ __launch_bounds__(256) void k_convert(
    const float* __restrict__ X, const float* __restrict__ W,
    unsigned short* __restrict__ Xb, unsigned short* __restrict__ BbT)
{
  __shared__ unsigned short wt[64][68];
  const int b = blockIdx.x;
  const int tid = threadIdx.x;

  if (b < 2048) {
    const int t = b * 256 + tid;
    const float4 v = reinterpret_cast<const float4*>(X)[t];
    ushort4 u;
    u.x = f2bf(v.x); u.y = f2bf(v.y); u.z = f2bf(v.z); u.w = f2bf(v.w);
    reinterpret_cast<ushort4*>(Xb)[t] = u;
  } else {
    const int b2 = b - 2048;
    const int h = b2 >> 3;
    const int f0 = (b2 & 7) << 6;
    const int fr = tid >> 2;
    const int rq = (tid & 3) << 4;
    const float* wp = W + (size_t)h * FF * RR + (size_t)(f0 + fr) * RR + rq;
#pragma unroll
    for (int v = 0; v < 4; ++v) {
      const float4 x = *reinterpret_cast<const float4*>(wp + v * 4);
      wt[rq + v * 4 + 0][fr] = f2bf(x.x);
      wt[rq + v * 4 + 1][fr] = f2bf(x.y);
      wt[rq + v * 4 + 2][fr] = f2bf(x.z);
      wt[rq + v * 4 + 3][fr] = f2bf(x.w);
    }
    __syncthreads();
    const int r = tid >> 2;
    unsigned short* op = BbT + (size_t)(h * 64 + r) * FF + f0 + ((tid & 3) << 4);
    int4 w0 = *reinterpret_cast<const int4*>(&wt[r][(tid & 3) << 4]);
    int4 w1 = *reinterpret_cast<const int4*>(&wt[r][((tid & 3) << 4) + 8]);
    *reinterpret_cast<int4*>(op) = w0;
    *reinterpret_cast<int4*>(op + 8) = w1;
  }
}

// ---------------------------------------------------------------------------
// K2 (mega): blocks [0,512): MFMA GEMM + fused a_srcT/a_dstT epilogue.
// blocks [512,1536): adjacency compaction + BIAS GATHER (hidden under GEMM).
// ---------------------------------------------------------------------------
__global__ __launch_bounds__(256) void k_mega(
    const unsigned short* __restrict__ Xb,
    const unsigned short* __restrict__ BbT,
    const float* __restrict__ sa,
    const float* __restrict__ adj,
    const float* __restrict__ bias,
    unsigned short* __restrict__ hiddenT,
    float* __restrict__ a_srcT,
    float* __restrict__ a_dstT,
    int* __restrict__ colsG,
    float* __restrict__ bvalsG,
    int* __restrict__ cnts)
{
  __shared__ unsigned short Als[64 * 32];
  __shared__ unsigned short Bls[64 * 32];
  __shared__ float redS[64][2];
  __shared__ float redD[64][2];
  const int b = blockIdx.x;
  const int tid = threadIdx.x;

  if (b < 512) {
    const int row0 = (b & 63) * 64;
    const int h = b >> 6;
    const int n0 = h * 64;
    const int l = tid & 63;
    const int wid = tid >> 6;
    const int wr = wid >> 1, wc = wid & 1;

    f32x4 acc[2][2];
#pragma unroll
    for (int a = 0; a < 2; ++a)
#pragma unroll
      for (int bb = 0; bb < 2; ++bb) acc[a][bb] = (f32x4){0.f, 0.f, 0.f, 0.f};

    const int srow = tid >> 2;
    const int skel = (tid & 3) * 8;

    for (int k0 = 0; k0 < FF; k0 += 32) {
      const int4 av = *reinterpret_cast<const int4*>(
          &Xb[(size_t)(row0 + srow) * FF + k0 + skel]);
      const int4 bv = *reinterpret_cast<const int4*>(
          &BbT[(size_t)(n0 + srow) * FF + k0 + skel]);
      __syncthreads();
      *reinterpret_cast<int4*>(&Als[tid * 8]) = av;
      *reinterpret_cast<int4*>(&Bls[tid * 8]) = bv;
      __syncthreads();

      const int ka = (l >> 4) * 8;
      const bf16x8 a0 = *reinterpret_cast<const bf16x8*>(&Als[(32 * wr + 0  + (l & 15)) * 32 + ka]);
      const bf16x8 a1 = *reinterpret_cast<const bf16x8*>(&Als[(32 * wr + 16 + (l & 15)) * 32 + ka]);
      const bf16x8 b0 = *reinterpret_cast<const bf16x8*>(&Bls[(32 * wc + 0  + (l & 15)) * 32 + ka]);
      const bf16x8 b1 = *reinterpret_cast<const bf16x8*>(&Bls[(32 * wc + 16 + (l & 15)) * 32 + ka]);
      acc[0][0] = __builtin_amdgcn_mfma_f32_16x16x32_bf16(a0, b0, acc[0][0], 0, 0, 0);
      acc[0][1] = __builtin_amdgcn_mfma_f32_16x16x32_bf16(a0, b1, acc[0][1], 0, 0, 0);
      acc[1][0] = __builtin_amdgcn_mfma_f32_16x16x32_bf16(a1, b0, acc[1][0], 0, 0, 0);
      acc[1][1] = __builtin_amdgcn_mfma_f32_16x16x32_bf16(a1, b1, acc[1][1], 0, 0, 0);
    }

    const int lg = l >> 4;
    const int lc = l & 15;

#pragma unroll
    for (int mi = 0; mi < 2; ++mi)
#pragma unroll
      for (int ni = 0; ni < 2; ++ni)
#pragma unroll
        for (int j = 0; j < 4; ++j) {
          const int rowg = row0 + 32 * wr + 16 * mi + (lg << 2) + j;
          const int colg = n0 + 32 * wc + 16 * ni + lc;
          hiddenT[(size_t)rowg * HR + colg] = f2bf(acc[mi][ni][j]);
        }

    float sS[2], sD[2];
#pragma unroll
    for (int ni = 0; ni < 2; ++ni) {
      const int col = 32 * wc + 16 * ni + lc;
      sS[ni] = sa[(size_t)h * 2 * RR + col];
      sD[ni] = sa[(size_t)h * 2 * RR + RR + col];
    }
#pragma unroll
    for (int mi = 0; mi < 2; ++mi)
#pragma unroll
      for (int j = 0; j < 4; ++j) {
        float ps = acc[mi][0][j] * sS[0] + acc[mi][1][j] * sS[1];
        float pd = acc[mi][0][j] * sD[0] + acc[mi][1][j] * sD[1];
#pragma unroll
        for (int off = 8; off >= 1; off >>= 1) {
          ps += __shfl_xor(ps, off);
          pd += __shfl_xor(pd, off);
        }
        if (lc == 0) {
          const int rl = 32 * wr + 16 * mi + (lg << 2) + j;
          redS[rl][wc] = ps;
          redD[rl][wc] = pd;
        }
      }
    __syncthreads();
    if (tid < 64) {
      a_srcT[(size_t)(row0 + tid) * HH + h] = redS[tid][0] + redS[tid][1];
      a_dstT[(size_t)(row0 + tid) * HH + h] = redD[tid][0] + redD[tid][1];
    }
  } else {
    const int lane = tid & 63;
    const int row = (b - 512) * 4 + (tid >> 6);
    const float* arow = adj + (size_t)row * NN;
    const float* brow = bias + (size_t)row * NN;
    unsigned long long pm = 0;
    {
      float4 buf[8];
#pragma unroll
      for (int c = 0; c < 8; ++c)
        buf[c] = *reinterpret_cast<const float4*>(&arow[c * 256 + (lane << 2)]);
#pragma unroll
      for (int c = 0; c < 8; ++c)
        pm |= (unsigned long long)nib4(buf[c]) << (4 * c);
#pragma unroll
      for (int c = 0; c < 8; ++c)
        buf[c] = *reinterpret_cast<const float4*>(&arow[(c + 8) * 256 + (lane << 2)]);
#pragma unroll
      for (int c = 0; c < 8; ++c)
        pm |= (unsigned long long)nib4(buf[c]) << (4 * c + 32);
    }
    const int cnt = __popcll(pm);
    int pfx = cnt;
#pragma unroll
    for (int off = 1; off < 64; off <<= 1) {
      const int o = __shfl_up(pfx, off);
      if (lane >= off) pfx += o;
    }
    int pos = pfx - cnt;
    unsigned long long m = pm;
    int* cg = colsG + (size_t)row * CAP;
    float* bg = bvalsG + (size_t)row * CAP;
    while (m) {
      const int bit = (int)__builtin_ctzll(m);
      m &= m - 1;
      if (pos < CAP) {
        const int col = ((bit >> 2) << 8) + (lane << 2) + (bit & 3);
        cg[pos] = col;
        bg[pos] = 0.01f * brow[col];   // scattered read hidden under GEMM
      }
      ++pos;
    }
    const int tot = __shfl(pfx, 63);
    for (int p = tot + lane; p < CAP; p += 64) { cg[p] = 0; bg[p] = 0.f; }
    if (lane == 63) cnts[row] = tot < CAP ? tot : CAP;
  }
}

// ---------------------------------------------------------------------------
// K3: 128 threads (2 waves) per row -> 16 blocks/CU -> ALL 4096 rows
// co-resident. Coalesced prologue (cols+bvals precomputed); 2-way agg.
// ---------------------------------------------------------------------------
__global__ __launch_bounds__(128) void k_gat_row(
    const int* __restrict__ colsG,
    const float* __restrict__ bvalsG,
    const int* __restrict__ cnts,
    const float* __restrict__ a_srcT,
    const float* __restrict__ a_dstT,
    const unsigned short* __restrict__ hiddenT,
    float* __restrict__ out)
{
  const int i = blockIdx.x;
  const int tid = threadIdx.x;   // 0..127

  __shared__ __align__(16) float att[HH][ATT_STRIDE];
  __shared__ int cols[CAP];
  __shared__ __align__(16) float accred[2][HR];

  // ---- prologue: all loads issued immediately (padded -> unconditional) ----
  const int c = colsG[(size_t)i * CAP + tid];
  const float b = bvalsG[(size_t)i * CAP + tid];
  const int count = cnts[i];
  const float4 d0 = *reinterpret_cast<const float4*>(&a_dstT[(size_t)c * HH]);
  const float4 d1 = *reinterpret_cast<const float4*>(&a_dstT[(size_t)c * HH + 4]);
  const float4 s0 = *reinterpret_cast<const float4*>(&a_srcT[(size_t)i * HH]);
  const float4 s1 = *reinterpret_cast<const float4*>(&a_srcT[(size_t)i * HH + 4]);

  {
    cols[tid] = c;
    float s;
    s = s0.x + d0.x + b; att[0][tid] = (s >= 0.f) ? s : 0.2f * s;
    s = s0.y + d0.y + b; att[1][tid] = (s >= 0.f) ? s : 0.2f * s;
    s = s0.z + d0.z + b; att[2][tid] = (s >= 0.f) ? s : 0.2f * s;
    s = s0.w + d0.w + b; att[3][tid] = (s >= 0.f) ? s : 0.2f * s;
    s = s1.x + d1.x + b; att[4][tid] = (s >= 0.f) ? s : 0.2f * s;
    s = s1.y + d1.y + b; att[5][tid] = (s >= 0.f) ? s : 0.2f * s;
    s = s1.z + d1.z + b; att[6][tid] = (s >= 0.f) ? s : 0.2f * s;
    s = s1.w + d1.w + b; att[7][tid] = (s >= 0.f) ? s : 0.2f * s;
  }
  __syncthreads();

  // ---- softmax: 16-lane group g = tid>>4 owns head g ----
  {
    const int g = tid >> 4;
    const int l = tid & 15;
    float* arow_h = att[g];
    float m = -3.0e38f;
    for (int t = l; t < count; t += 16) m = fmaxf(m, arow_h[t]);
#pragma unroll
    for (int o = 8; o >= 1; o >>= 1) m = fmaxf(m, __shfl_xor(m, o));
    float ssum = 0.f;
    for (int t = l; t < count; t += 16) {
      const float e = __expf(arow_h[t] - m);
      arow_h[t] = e;
      ssum += e;
    }
#pragma unroll
    for (int o = 8; o >= 1; o >>= 1) ssum += __shfl_xor(ssum, o);
    const float inv = 1.0f / ssum;
    for (int t = l; t < count; t += 16) arow_h[t] *= inv;
  }
  __syncthreads();

  // ---- aggregation: 2 groups of 64; thread owns 8 outputs (1 int4/neighbor) ----
  {
    const int g2 = tid >> 6;
    const int o0 = (tid & 63) << 3;
    const float* attrow = att[o0 >> 6];
    const unsigned short* hb = hiddenT + o0;
    const int half = (count + 1) >> 1;
    const int t0 = g2 * half;
    const int t1 = min(t0 + half, count);
    float4 accA = make_float4(0.f, 0.f, 0.f, 0.f);
    float4 accB = make_float4(0.f, 0.f, 0.f, 0.f);
    for (int t = t0; t < t1; ++t) {
      const int cc = cols[t];
      const float a = attrow[t];
      const ushort4 ua = *reinterpret_cast<const ushort4*>(hb + (size_t)cc * HR);
      const ushort4 ub = *reinterpret_cast<const ushort4*>(hb + (size_t)cc * HR + 4);
      accA.x += a * bf2f(ua.x); accA.y += a * bf2f(ua.y);
      accA.z += a * bf2f(ua.z); accA.w += a * bf2f(ua.w);
      accB.x += a * bf2f(ub.x); accB.y += a * bf2f(ub.y);
      accB.z += a * bf2f(ub.z); accB.w += a * bf2f(ub.w);
    }
    *reinterpret_cast<float4*>(&accred[g2][o0]) = accA;
    *reinterpret_cast<float4*>(&accred[g2][o0 + 4]) = accB;
  }
  __syncthreads();
  {
    const int o = tid << 2;
    const float4 v0 = *reinterpret_cast<const float4*>(&accred[0][o]);
    const float4 v1 = *reinterpret_cast<const float4*>(&accred[1][o]);
    const float4 r = make_float4(v0.x + v1.x, v0.y + v1.y, v0.z + v1.z, v0.w + v1.w);
    *reinterpret_cast<float4*>(&out[(size_t)i * HR + o]) = r;
  }
}

extern "C" void kernel_launch(void* const* d_in, const int* in_sizes, int n_in,
                              void* d_out, int out_size, void* d_ws, size_t ws_size,
                              hipStream_t stream) {
  const float* X    = (const float*)d_in[0];   // [N,F]
  const float* adj  = (const float*)d_in[1];   // [N,N]
  const float* W    = (const float*)d_in[2];   // [H,F,R]
  const float* sa   = (const float*)d_in[3];   // [H,2R]
  const float* bias = (const float*)d_in[4];   // [N,N]
  float* out = (float*)d_out;                  // [N, H*R]

  unsigned short* hiddenT = (unsigned short*)d_ws;        // [N][512] bf16, 4 MB
  unsigned short* Xb  = hiddenT + (size_t)NN * HR;        // [N][512] bf16, 4 MB
  unsigned short* BbT = Xb + (size_t)NN * FF;             // [512][512] bf16, 512 KB
  float* a_srcT = (float*)(BbT + (size_t)HR * FF);        // [N][H], 128 KB
  float* a_dstT = a_srcT + (size_t)NN * HH;               // [N][H], 128 KB
  int* cnts     = (int*)(a_dstT + (size_t)NN * HH);       // [N], 16 KB
  int* colsG    = cnts + NN;                              // [N][CAP], 2 MB
  float* bvalsG = (float*)(colsG + (size_t)NN * CAP);     // [N][CAP], 2 MB

  k_convert<<<dim3(2112), 256, 0, stream>>>(X, W, Xb, BbT);
  k_mega<<<dim3(1536), 256, 0, stream>>>(Xb, BbT, sa, adj, bias, hiddenT,
                                         a_srcT, a_dstT, colsG, bvalsG, cnts);
  k_gat_row<<<dim3(NN), 128, 0, stream>>>(colsG, bvalsG, cnts, a_srcT, a_dstT, hiddenT, out);
}